// Round 1
// baseline (1554.834 us; speedup 1.0000x reference)
//
#include <hip/hip_runtime.h>

#define D 128
#define BN_EPS 1e-5f

// ---- degree count: deg[col[e]] += 1 ----
__global__ __launch_bounds__(256) void k_deg(const int* __restrict__ col,
                                             float* __restrict__ deg, int E) {
  int i = blockIdx.x * 256 + threadIdx.x;
  if (i < E) atomicAdd(&deg[col[i]], 1.0f);
}

// ---- dinv = rsqrt(deg + 1)  (+1 = self loop) ----
__global__ __launch_bounds__(256) void k_dinv(float* __restrict__ deg, int n) {
  int i = blockIdx.x * 256 + threadIdx.x;
  if (i < n) deg[i] = rsqrtf(deg[i] + 1.0f);
}

// ---- h = x @ W  (fp32 vector ALU; W fully in LDS; 4x4 reg tile/thread) ----
__global__ __launch_bounds__(256) void k_matmul(const float* __restrict__ x,
                                                const float* __restrict__ W,
                                                float* __restrict__ h, int n) {
  __shared__ float Ws[D * D];      // 64 KB
  __shared__ float xs[32 * D];     // 16 KB
  const int tid = threadIdx.x;
  // load W (coalesced float4)
  for (int i = tid * 4; i < D * D; i += 256 * 4)
    *(float4*)(Ws + i) = *(const float4*)(W + i);
  const long rbase = (long)blockIdx.x * 32;
  for (int i = tid * 4; i < 32 * D; i += 256 * 4) {
    long r = rbase + (i >> 7);
    float4 v = make_float4(0.f, 0.f, 0.f, 0.f);
    if (r < n) v = *(const float4*)(x + r * D + (i & (D - 1)));
    *(float4*)(xs + i) = v;
  }
  __syncthreads();

  const int c0 = (tid & 31) * 4;        // 4 consecutive cols
  const int r0 = (tid >> 5) * 4;        // 4 consecutive rows
  float acc[4][4] = {};
  for (int k = 0; k < D; k += 4) {
    float4 xv[4], wv[4];
#pragma unroll
    for (int j = 0; j < 4; ++j) xv[j] = *(const float4*)(xs + (r0 + j) * D + k);      // broadcast reads
#pragma unroll
    for (int kk = 0; kk < 4; ++kk) wv[kk] = *(const float4*)(Ws + (k + kk) * D + c0); // stride-1 b128
#pragma unroll
    for (int j = 0; j < 4; ++j) {
      const float xk0 = xv[j].x, xk1 = xv[j].y, xk2 = xv[j].z, xk3 = xv[j].w;
      acc[j][0] += xk0 * wv[0].x + xk1 * wv[1].x + xk2 * wv[2].x + xk3 * wv[3].x;
      acc[j][1] += xk0 * wv[0].y + xk1 * wv[1].y + xk2 * wv[2].y + xk3 * wv[3].y;
      acc[j][2] += xk0 * wv[0].z + xk1 * wv[1].z + xk2 * wv[2].z + xk3 * wv[3].z;
      acc[j][3] += xk0 * wv[0].w + xk1 * wv[1].w + xk2 * wv[2].w + xk3 * wv[3].w;
    }
  }
#pragma unroll
  for (int j = 0; j < 4; ++j) {
    long r = rbase + r0 + j;
    if (r < n)
      *(float4*)(h + r * D + c0) = make_float4(acc[j][0], acc[j][1], acc[j][2], acc[j][3]);
  }
}

// ---- agg init = self-loop contribution: agg[i,:] = h[i,:] * dinv[i]^2 ----
__global__ __launch_bounds__(256) void k_selfloop(const float* __restrict__ h,
                                                  const float* __restrict__ dinv,
                                                  float* __restrict__ agg, long n4) {
  long i = (long)blockIdx.x * 256 + threadIdx.x;   // float4 index; 32 per row
  if (i < n4) {
    long r = i >> 5;
    float s = dinv[r] * dinv[r];
    float4 v = ((const float4*)h)[i];
    v.x *= s; v.y *= s; v.z *= s; v.w *= s;
    ((float4*)agg)[i] = v;
  }
}

// ---- edge scatter: agg[col] += h[row] * dinv[row]*dinv[col]  (32 lanes/edge) ----
__global__ __launch_bounds__(256) void k_scatter(const int* __restrict__ row,
                                                 const int* __restrict__ col,
                                                 const float* __restrict__ dinv,
                                                 const float* __restrict__ h,
                                                 float* __restrict__ agg, int E) {
  long t = (long)blockIdx.x * 256 + threadIdx.x;
  long e = t >> 5;
  if (e >= E) return;
  int lane = (int)(t & 31);
  int r = row[e], c = col[e];
  float nrm = dinv[r] * dinv[c];
  float4 v = ((const float4*)(h + (long)r * D))[lane];
  float* dst = agg + (long)c * D + lane * 4;
  atomicAdd(dst + 0, v.x * nrm);
  atomicAdd(dst + 1, v.y * nrm);
  atomicAdd(dst + 2, v.z * nrm);
  atomicAdd(dst + 3, v.w * nrm);
}

// ---- per-column sums for BN (coalesced; col(t) = t & 127 invariant) ----
__global__ __launch_bounds__(256) void k_bnstats(const float* __restrict__ agg,
                                                 float* __restrict__ sums,
                                                 float* __restrict__ sumsq, long total) {
  float s = 0.f, sq = 0.f;
  for (long i = (long)blockIdx.x * 256 + threadIdx.x; i < total; i += (long)gridDim.x * 256) {
    float v = agg[i];
    s += v; sq += v * v;
  }
  __shared__ float rs[256], rq[256];
  int tid = threadIdx.x;
  rs[tid] = s; rq[tid] = sq;
  __syncthreads();
  if (tid < 128) {
    atomicAdd(&sums[tid], rs[tid] + rs[tid + 128]);
    atomicAdd(&sumsq[tid], rq[tid] + rq[tid + 128]);
  }
}

// ---- fold stats to scale/shift (bias b cancels in BN exactly) ----
__global__ void k_bnfin(const float* __restrict__ sums, const float* __restrict__ sumsq,
                        const float* __restrict__ gamma, const float* __restrict__ beta,
                        float* __restrict__ scale, float* __restrict__ shift, float invN) {
  int d = threadIdx.x;
  float mean = sums[d] * invN;
  float var = sumsq[d] * invN - mean * mean;
  float sc = gamma[d] * rsqrtf(var + BN_EPS);
  scale[d] = sc;
  shift[d] = beta[d] - mean * sc;
}

// ---- out = relu(agg*scale + shift) + x  (in-place on d_out) ----
__global__ __launch_bounds__(256) void k_final(const float* __restrict__ agg,
                                               const float* __restrict__ x,
                                               const float* __restrict__ scale,
                                               const float* __restrict__ shift,
                                               float* __restrict__ out, long n4) {
  long i = (long)blockIdx.x * 256 + threadIdx.x;
  if (i < n4) {
    int c4 = (int)(i & 31) * 4;
    float4 v = ((const float4*)agg)[i];
    float4 xr = ((const float4*)x)[i];
    float4 sc = *(const float4*)(scale + c4);
    float4 sh = *(const float4*)(shift + c4);
    float4 o;
    o.x = fmaxf(v.x * sc.x + sh.x, 0.f) + xr.x;
    o.y = fmaxf(v.y * sc.y + sh.y, 0.f) + xr.y;
    o.z = fmaxf(v.z * sc.z + sh.z, 0.f) + xr.z;
    o.w = fmaxf(v.w * sc.w + sh.w, 0.f) + xr.w;
    ((float4*)out)[i] = o;
  }
}

extern "C" void kernel_launch(void* const* d_in, const int* in_sizes, int n_in,
                              void* d_out, int out_size, void* d_ws, size_t ws_size,
                              hipStream_t stream) {
  const float* x     = (const float*)d_in[0];
  const int*   ei    = (const int*)d_in[1];   // [2,E] int32 (jax x64 disabled)
  const float* W     = (const float*)d_in[2];
  // d_in[3] = b : cancels exactly in BatchNorm (shifts mean by b) — skipped
  const float* gamma = (const float*)d_in[4];
  const float* beta  = (const float*)d_in[5];
  float* out = (float*)d_out;

  const int N = in_sizes[0] / D;
  const int E = in_sizes[1] / 2;
  const int* row = ei;
  const int* col = ei + E;

  float* h     = (float*)d_ws;               // N*D floats (25.6 MB)
  float* dinv  = h + (size_t)N * D;          // N
  float* sums  = dinv + N;                   // D
  float* sumsq = sums + D;                   // D
  float* scale = sumsq + D;                  // D
  float* shift = scale + D;                  // D

  hipMemsetAsync(dinv, 0, sizeof(float) * (size_t)N, stream);
  hipMemsetAsync(sums, 0, sizeof(float) * 2 * D, stream);

  k_deg<<<(E + 255) / 256, 256, 0, stream>>>(col, dinv, E);
  k_dinv<<<(N + 255) / 256, 256, 0, stream>>>(dinv, N);
  k_matmul<<<(N + 31) / 32, 256, 0, stream>>>(x, W, h, N);

  const long n4 = (long)N * (D / 4);
  k_selfloop<<<(int)((n4 + 255) / 256), 256, 0, stream>>>(h, dinv, out, n4);
  k_scatter<<<(int)(((long)E * 32 + 255) / 256), 256, 0, stream>>>(row, col, dinv, h, out, E);
  k_bnstats<<<512, 256, 0, stream>>>(out, sums, sumsq, (long)N * D);
  k_bnfin<<<1, D, 0, stream>>>(sums, sumsq, gamma, beta, scale, shift, 1.0f / (float)N);
  k_final<<<(int)((n4 + 255) / 256), 256, 0, stream>>>(out, x, scale, shift, out, n4);
}

// Round 2
// 316.799 us; speedup vs baseline: 4.9080x; 4.9080x over previous
//
#include <hip/hip_runtime.h>

#define D 128
#define BN_EPS 1e-5f

// ---- in-degree count (int atomics) ----
__global__ __launch_bounds__(256) void k_deg(const int* __restrict__ col,
                                             int* __restrict__ deg, int E) {
  int i = blockIdx.x * 256 + threadIdx.x;
  if (i < E) atomicAdd(&deg[col[i]], 1);
}

// ---- dinv = rsqrt(deg + 1)  (+1 = self loop) ----
__global__ __launch_bounds__(256) void k_dinv(const int* __restrict__ deg,
                                              float* __restrict__ dinv, int n) {
  int i = blockIdx.x * 256 + threadIdx.x;
  if (i < n) dinv[i] = rsqrtf((float)deg[i] + 1.0f);
}

// ---- exclusive scan of deg -> ptr, 2048 elems/block ----
__global__ __launch_bounds__(256) void k_scan1(const int* __restrict__ deg,
                                               int* __restrict__ ptr,
                                               int* __restrict__ bsum, int n) {
  __shared__ int lds[256];
  const int tid = threadIdx.x;
  const int base = blockIdx.x * 2048 + tid * 8;
  int v[8];
  int tsum = 0;
#pragma unroll
  for (int j = 0; j < 8; ++j) {
    v[j] = (base + j < n) ? deg[base + j] : 0;
    tsum += v[j];
  }
  lds[tid] = tsum;
  __syncthreads();
#pragma unroll
  for (int off = 1; off < 256; off <<= 1) {
    int t = (tid >= off) ? lds[tid - off] : 0;
    __syncthreads();
    lds[tid] += t;
    __syncthreads();
  }
  int run = lds[tid] - tsum;   // exclusive prefix of this thread's chunk
  if (tid == 255) bsum[blockIdx.x] = lds[255];
#pragma unroll
  for (int j = 0; j < 8; ++j) {
    if (base + j < n) ptr[base + j] = run;
    run += v[j];
  }
}

__global__ void k_scan2(int* __restrict__ bsum, int nb) {
  if (threadIdx.x == 0) {
    int run = 0;
    for (int i = 0; i < nb; ++i) { int t = bsum[i]; bsum[i] = run; run += t; }
  }
}

__global__ __launch_bounds__(256) void k_scan3(int* __restrict__ ptr,
                                               const int* __restrict__ bsum, int n) {
  int i = blockIdx.x * 256 + threadIdx.x;
  if (i < n) ptr[i] += bsum[i >> 11];
}

// ---- g = (x @ W) * dinv[row]  (fp32 vector ALU; W in LDS; 4x4 reg tile) ----
__global__ __launch_bounds__(256) void k_matmul(const float* __restrict__ x,
                                                const float* __restrict__ W,
                                                const float* __restrict__ dinv,
                                                float* __restrict__ g, int n) {
  __shared__ float Ws[D * D];      // 64 KB
  __shared__ float xs[32 * D];     // 16 KB
  const int tid = threadIdx.x;
  for (int i = tid * 4; i < D * D; i += 256 * 4)
    *(float4*)(Ws + i) = *(const float4*)(W + i);
  const long rbase = (long)blockIdx.x * 32;
  for (int i = tid * 4; i < 32 * D; i += 256 * 4) {
    long r = rbase + (i >> 7);
    float4 v = make_float4(0.f, 0.f, 0.f, 0.f);
    if (r < n) v = *(const float4*)(x + r * D + (i & (D - 1)));
    *(float4*)(xs + i) = v;
  }
  __syncthreads();

  const int c0 = (tid & 31) * 4;
  const int r0 = (tid >> 5) * 4;
  float acc[4][4] = {};
  for (int k = 0; k < D; k += 4) {
    float4 xv[4], wv[4];
#pragma unroll
    for (int j = 0; j < 4; ++j) xv[j] = *(const float4*)(xs + (r0 + j) * D + k);
#pragma unroll
    for (int kk = 0; kk < 4; ++kk) wv[kk] = *(const float4*)(Ws + (k + kk) * D + c0);
#pragma unroll
    for (int j = 0; j < 4; ++j) {
      const float xk0 = xv[j].x, xk1 = xv[j].y, xk2 = xv[j].z, xk3 = xv[j].w;
      acc[j][0] += xk0 * wv[0].x + xk1 * wv[1].x + xk2 * wv[2].x + xk3 * wv[3].x;
      acc[j][1] += xk0 * wv[0].y + xk1 * wv[1].y + xk2 * wv[2].y + xk3 * wv[3].y;
      acc[j][2] += xk0 * wv[0].z + xk1 * wv[1].z + xk2 * wv[2].z + xk3 * wv[3].z;
      acc[j][3] += xk0 * wv[0].w + xk1 * wv[1].w + xk2 * wv[2].w + xk3 * wv[3].w;
    }
  }
#pragma unroll
  for (int j = 0; j < 4; ++j) {
    long r = rbase + r0 + j;
    if (r < n) {
      float s = dinv[r];
      *(float4*)(g + r * D + c0) =
          make_float4(acc[j][0] * s, acc[j][1] * s, acc[j][2] * s, acc[j][3] * s);
    }
  }
}

// ---- counting-sort edges by target: srcs[pos] = row  (shifts ptr by deg) ----
__global__ __launch_bounds__(256) void k_bin(const int* __restrict__ row,
                                             const int* __restrict__ col,
                                             int* __restrict__ ptr,
                                             int* __restrict__ srcs, int E) {
  int e = blockIdx.x * 256 + threadIdx.x;
  if (e < E) {
    int p = atomicAdd(&ptr[col[e]], 1);
    srcs[p] = row[e];
  }
}

// ---- per-node gather-reduce: out[c] = dinv[c] * (sum g[srcs] + g[c]) ----
// one 64-lane wave per node, float2 per lane.
// after k_bin, node c's list spans [ (c? ptr[c-1] : 0), ptr[c] )
__global__ __launch_bounds__(256) void k_agg(const int* __restrict__ srcs,
                                             const int* __restrict__ ptr,
                                             const float* __restrict__ g,
                                             const float* __restrict__ dinv,
                                             float* __restrict__ out, int n) {
  int wid = (blockIdx.x * 256 + threadIdx.x) >> 6;   // node id
  if (wid >= n) return;
  int lane = threadIdx.x & 63;
  int start = (wid == 0) ? 0 : ptr[wid - 1];
  int end = ptr[wid];
  const float* gl = g + lane * 2;
  float2 acc = *(const float2*)(gl + (long)wid * D);   // self-loop term g[c]
  int i = start;
  for (; i + 1 < end; i += 2) {
    int r0 = srcs[i], r1 = srcs[i + 1];
    float2 v0 = *(const float2*)(gl + (long)r0 * D);
    float2 v1 = *(const float2*)(gl + (long)r1 * D);
    acc.x += v0.x + v1.x;
    acc.y += v0.y + v1.y;
  }
  if (i < end) {
    int r0 = srcs[i];
    float2 v0 = *(const float2*)(gl + (long)r0 * D);
    acc.x += v0.x;
    acc.y += v0.y;
  }
  float dc = dinv[wid];
  acc.x *= dc; acc.y *= dc;
  *(float2*)(out + (long)wid * D + lane * 2) = acc;
}

// ---- per-column sums for BN ----
__global__ __launch_bounds__(256) void k_bnstats(const float* __restrict__ agg,
                                                 float* __restrict__ sums,
                                                 float* __restrict__ sumsq, long total) {
  float s = 0.f, sq = 0.f;
  for (long i = (long)blockIdx.x * 256 + threadIdx.x; i < total; i += (long)gridDim.x * 256) {
    float v = agg[i];
    s += v; sq += v * v;
  }
  __shared__ float rs[256], rq[256];
  int tid = threadIdx.x;
  rs[tid] = s; rq[tid] = sq;
  __syncthreads();
  if (tid < 128) {
    atomicAdd(&sums[tid], rs[tid] + rs[tid + 128]);
    atomicAdd(&sumsq[tid], rq[tid] + rq[tid + 128]);
  }
}

// ---- fold stats (bias b cancels in BN exactly) ----
__global__ void k_bnfin(const float* __restrict__ sums, const float* __restrict__ sumsq,
                        const float* __restrict__ gamma, const float* __restrict__ beta,
                        float* __restrict__ scale, float* __restrict__ shift, float invN) {
  int d = threadIdx.x;
  float mean = sums[d] * invN;
  float var = sumsq[d] * invN - mean * mean;
  float sc = gamma[d] * rsqrtf(var + BN_EPS);
  scale[d] = sc;
  shift[d] = beta[d] - mean * sc;
}

// ---- out = relu(agg*scale + shift) + x ----
__global__ __launch_bounds__(256) void k_final(const float* __restrict__ agg,
                                               const float* __restrict__ x,
                                               const float* __restrict__ scale,
                                               const float* __restrict__ shift,
                                               float* __restrict__ out, long n4) {
  long i = (long)blockIdx.x * 256 + threadIdx.x;
  if (i < n4) {
    int c4 = (int)(i & 31) * 4;
    float4 v = ((const float4*)agg)[i];
    float4 xr = ((const float4*)x)[i];
    float4 sc = *(const float4*)(scale + c4);
    float4 sh = *(const float4*)(shift + c4);
    float4 o;
    o.x = fmaxf(v.x * sc.x + sh.x, 0.f) + xr.x;
    o.y = fmaxf(v.y * sc.y + sh.y, 0.f) + xr.y;
    o.z = fmaxf(v.z * sc.z + sh.z, 0.f) + xr.z;
    o.w = fmaxf(v.w * sc.w + sh.w, 0.f) + xr.w;
    ((float4*)out)[i] = o;
  }
}

extern "C" void kernel_launch(void* const* d_in, const int* in_sizes, int n_in,
                              void* d_out, int out_size, void* d_ws, size_t ws_size,
                              hipStream_t stream) {
  const float* x     = (const float*)d_in[0];
  const int*   ei    = (const int*)d_in[1];
  const float* W     = (const float*)d_in[2];
  // d_in[3] = b : cancels exactly in BatchNorm — skipped
  const float* gamma = (const float*)d_in[4];
  const float* beta  = (const float*)d_in[5];
  float* out = (float*)d_out;

  const int N = in_sizes[0] / D;
  const int E = in_sizes[1] / 2;
  const int* row = ei;
  const int* col = ei + E;

  // workspace layout
  float* g     = (float*)d_ws;               // N*D floats (25.6 MB)
  float* dinv  = g + (size_t)N * D;          // N
  float* sums  = dinv + N;                   // D
  float* sumsq = sums + D;                   // D
  float* scale = sumsq + D;                  // D
  float* shift = scale + D;                  // D
  int*   deg   = (int*)(shift + D);          // N
  int*   ptr   = deg + N;                    // N
  int*   bsum  = ptr + N;                    // 32
  int*   srcs  = bsum + 32;                  // E (3.2 MB)

  hipMemsetAsync(deg, 0, sizeof(int) * (size_t)N, stream);
  hipMemsetAsync(sums, 0, sizeof(float) * 2 * D, stream);

  k_deg<<<(E + 255) / 256, 256, 0, stream>>>(col, deg, E);
  k_dinv<<<(N + 255) / 256, 256, 0, stream>>>(deg, dinv, N);

  const int nb1 = (N + 2047) / 2048;
  k_scan1<<<nb1, 256, 0, stream>>>(deg, ptr, bsum, N);
  k_scan2<<<1, 64, 0, stream>>>(bsum, nb1);
  k_scan3<<<(N + 255) / 256, 256, 0, stream>>>(ptr, bsum, N);

  k_matmul<<<(N + 31) / 32, 256, 0, stream>>>(x, W, dinv, g, N);
  k_bin<<<(E + 255) / 256, 256, 0, stream>>>(row, col, ptr, srcs, E);
  k_agg<<<(N * 64 + 255) / 256, 256, 0, stream>>>(srcs, ptr, g, dinv, out, N);

  k_bnstats<<<512, 256, 0, stream>>>(out, sums, sumsq, (long)N * D);
  k_bnfin<<<1, D, 0, stream>>>(sums, sumsq, gamma, beta, scale, shift, 1.0f / (float)N);

  const long n4 = (long)N * (D / 4);
  k_final<<<(int)((n4 + 255) / 256), 256, 0, stream>>>(out, x, scale, shift, out, n4);
}

// Round 12
// 261.806 us; speedup vs baseline: 5.9389x; 1.2101x over previous
//
#include <hip/hip_runtime.h>

#define D 128
#define BN_EPS 1e-5f

typedef __attribute__((ext_vector_type(8))) short short8;
typedef __attribute__((ext_vector_type(4))) float f32x4;

static __device__ __forceinline__ unsigned short f2bf(float f) {
  unsigned u = __float_as_uint(f);
  u += 0x7fff + ((u >> 16) & 1);           // round-to-nearest-even
  return (unsigned short)(u >> 16);
}
static __device__ __forceinline__ float bf2f(unsigned short u) {
  return __uint_as_float(((unsigned)u) << 16);
}

// ---- in-degree count (int atomics) ----
__global__ __launch_bounds__(256) void k_deg(const int* __restrict__ col,
                                             int* __restrict__ deg, int E) {
  int i = blockIdx.x * 256 + threadIdx.x;
  if (i < E) atomicAdd(&deg[col[i]], 1);
}

// ---- exclusive scan of deg -> ptr (2048/block) + fused dinv = rsqrt(deg+1) ----
__global__ __launch_bounds__(256) void k_scan1(const int* __restrict__ deg,
                                               int* __restrict__ ptr,
                                               int* __restrict__ bsum,
                                               float* __restrict__ dinv, int n) {
  __shared__ int lds[256];
  const int tid = threadIdx.x;
  const int base = blockIdx.x * 2048 + tid * 8;
  int v[8];
  int tsum = 0;
#pragma unroll
  for (int j = 0; j < 8; ++j) {
    v[j] = (base + j < n) ? deg[base + j] : 0;
    if (base + j < n) dinv[base + j] = rsqrtf((float)v[j] + 1.0f);
    tsum += v[j];
  }
  lds[tid] = tsum;
  __syncthreads();
#pragma unroll
  for (int off = 1; off < 256; off <<= 1) {
    int t = (tid >= off) ? lds[tid - off] : 0;
    __syncthreads();
    lds[tid] += t;
    __syncthreads();
  }
  int run = lds[tid] - tsum;
  if (tid == 255) bsum[blockIdx.x] = lds[255];
#pragma unroll
  for (int j = 0; j < 8; ++j) {
    if (base + j < n) ptr[base + j] = run;
    run += v[j];
  }
}

__global__ void k_scan2(int* __restrict__ bsum, int nb) {
  if (threadIdx.x == 0) {
    int run = 0;
    for (int i = 0; i < nb; ++i) { int t = bsum[i]; bsum[i] = run; run += t; }
  }
}

__global__ __launch_bounds__(256) void k_scan3(int* __restrict__ ptr,
                                               const int* __restrict__ bsum, int n) {
  int i = blockIdx.x * 256 + threadIdx.x;
  if (i < n) ptr[i] += bsum[i >> 11];
}

// ---- Wt[c][k] = bf16(W[k][c])  (coalesced read, scattered 2B writes, 64KB) ----
__global__ __launch_bounds__(256) void k_prep(const float* __restrict__ W,
                                              unsigned short* __restrict__ Wt) {
  int i = blockIdx.x * 256 + threadIdx.x;   // i = k*128 + c
  int k = i >> 7, c = i & 127;
  Wt[c * D + k] = f2bf(W[i]);
}

// ---- g_bf16 = bf16( (x @ W) * dinv[row] )  via MFMA 16x16x32 bf16 ----
// block = 256 thr = 4 waves, 64 rows/block (16 rows/wave, all 128 cols).
// Wt staged in LDS with 16B-chunk XOR swizzle: byte ^= (row&7)<<4.
__global__ __launch_bounds__(256) void k_mm(const float* __restrict__ x,
                                            const unsigned short* __restrict__ Wt,
                                            const float* __restrict__ dinv,
                                            unsigned short* __restrict__ g, int n) {
  __shared__ unsigned short wt[D * D];      // 32 KB
  const int tid = threadIdx.x;
  for (int i = tid; i < D * D / 8; i += 256) {      // 2048 x 16B chunks
    int row = i >> 4, c16 = i & 15;
    int dby = (c16 * 16) ^ ((row & 7) << 4);
    *(uint4*)(&wt[row * D + (dby >> 1)]) = ((const uint4*)Wt)[i];
  }
  __syncthreads();

  const int lane = tid & 63;
  const int wave = tid >> 6;
  const int row0 = blockIdx.x * 64 + wave * 16;
  const int lr = lane & 15;                  // row-in-tile (A) / col-in-tile (B,D)
  const int lk = lane >> 4;                  // k-chunk select
  const int arow = row0 + lr;

  short8 a[4] = {};
  if (arow < n) {
    const float* xp = x + (long)arow * D + lk * 8;
#pragma unroll
    for (int kk = 0; kk < 4; ++kk) {
      float4 v0 = *(const float4*)(xp + kk * 32);
      float4 v1 = *(const float4*)(xp + kk * 32 + 4);
      short8 t;
      t[0] = (short)f2bf(v0.x); t[1] = (short)f2bf(v0.y);
      t[2] = (short)f2bf(v0.z); t[3] = (short)f2bf(v0.w);
      t[4] = (short)f2bf(v1.x); t[5] = (short)f2bf(v1.y);
      t[6] = (short)f2bf(v1.z); t[7] = (short)f2bf(v1.w);
      a[kk] = t;
    }
  }

  f32x4 acc[8] = {};
#pragma unroll
  for (int ct = 0; ct < 8; ++ct) {
    const int colt = ct * 16 + lr;
    const unsigned short* wrow = &wt[colt * D];
    const int swz = (colt & 7) << 4;
#pragma unroll
    for (int kk = 0; kk < 4; ++kk) {
      int by = (kk * 64 + lk * 16) ^ swz;
      short8 b = *(const short8*)(&wrow[by >> 1]);
      acc[ct] = __builtin_amdgcn_mfma_f32_16x16x32_bf16(a[kk], b, acc[ct], 0, 0, 0);
    }
  }

  // C/D layout: col = lane&15, row = (lane>>4)*4 + reg
  float dv[4];
#pragma unroll
  for (int rr = 0; rr < 4; ++rr) {
    int grow = row0 + lk * 4 + rr;
    dv[rr] = (grow < n) ? dinv[grow] : 0.f;
  }
#pragma unroll
  for (int ct = 0; ct < 8; ++ct) {
#pragma unroll
    for (int rr = 0; rr < 4; ++rr) {
      int grow = row0 + lk * 4 + rr;
      if (grow < n)
        g[(long)grow * D + ct * 16 + lr] = f2bf(acc[ct][rr] * dv[rr]);
    }
  }
}

// ---- counting-sort edges by target: srcs[pos] = row ----
__global__ __launch_bounds__(256) void k_bin(const int* __restrict__ row,
                                             const int* __restrict__ col,
                                             int* __restrict__ ptr,
                                             int* __restrict__ srcs, int E) {
  int e = blockIdx.x * 256 + threadIdx.x;
  if (e < E) {
    int p = atomicAdd(&ptr[col[e]], 1);
    srcs[p] = row[e];
  }
}

// ---- per-node gather-reduce over bf16 g: out[c] = dinv[c]*(sum g[srcs] + g[c]) ----
// one 64-lane wave per node, ushort2 (2 bf16) per lane.
__global__ __launch_bounds__(256) void k_agg(const int* __restrict__ srcs,
                                             const int* __restrict__ ptr,
                                             const ushort2* __restrict__ g2,
                                             const float* __restrict__ dinv,
                                             float* __restrict__ out, int n) {
  int wid = (blockIdx.x * 256 + threadIdx.x) >> 6;
  if (wid >= n) return;
  int lane = threadIdx.x & 63;
  int start = (wid == 0) ? 0 : ptr[wid - 1];
  int end = ptr[wid];
  const ushort2* gl = g2 + lane;             // row stride = 64 ushort2
  ushort2 sv = gl[(long)wid * 64];
  float ax = bf2f(sv.x), ay = bf2f(sv.y);    // self-loop term
  int i = start;
  for (; i + 3 < end; i += 4) {
    ushort2 v0 = gl[(long)srcs[i] * 64];
    ushort2 v1 = gl[(long)srcs[i + 1] * 64];
    ushort2 v2 = gl[(long)srcs[i + 2] * 64];
    ushort2 v3 = gl[(long)srcs[i + 3] * 64];
    ax += bf2f(v0.x) + bf2f(v1.x) + bf2f(v2.x) + bf2f(v3.x);
    ay += bf2f(v0.y) + bf2f(v1.y) + bf2f(v2.y) + bf2f(v3.y);
  }
  for (; i < end; ++i) {
    ushort2 v0 = gl[(long)srcs[i] * 64];
    ax += bf2f(v0.x);
    ay += bf2f(v0.y);
  }
  float dc = dinv[wid];
  *(float2*)(out + (long)wid * D + lane * 2) = make_float2(ax * dc, ay * dc);
}

// ---- per-column sums for BN ----
__global__ __launch_bounds__(256) void k_bnstats(const float* __restrict__ agg,
                                                 float* __restrict__ sums,
                                                 float* __restrict__ sumsq, long total) {
  float s = 0.f, sq = 0.f;
  for (long i = (long)blockIdx.x * 256 + threadIdx.x; i < total; i += (long)gridDim.x * 256) {
    float v = agg[i];
    s += v; sq += v * v;
  }
  __shared__ float rs[256], rq[256];
  int tid = threadIdx.x;
  rs[tid] = s; rq[tid] = sq;
  __syncthreads();
  if (tid < 128) {
    atomicAdd(&sums[tid], rs[tid] + rs[tid + 128]);
    atomicAdd(&sumsq[tid], rq[tid] + rq[tid + 128]);
  }
}

// ---- fold stats (bias b cancels in BN exactly) ----
__global__ void k_bnfin(const float* __restrict__ sums, const float* __restrict__ sumsq,
                        const float* __restrict__ gamma, const float* __restrict__ beta,
                        float* __restrict__ scale, float* __restrict__ shift, float invN) {
  int d = threadIdx.x;
  float mean = sums[d] * invN;
  float var = sumsq[d] * invN - mean * mean;
  float sc = gamma[d] * rsqrtf(var + BN_EPS);
  scale[d] = sc;
  shift[d] = beta[d] - mean * sc;
}

// ---- out = relu(agg*scale + shift) + x ----
__global__ __launch_bounds__(256) void k_final(const float* __restrict__ agg,
                                               const float* __restrict__ x,
                                               const float* __restrict__ scale,
                                               const float* __restrict__ shift,
                                               float* __restrict__ out, long n4) {
  long i = (long)blockIdx.x * 256 + threadIdx.x;
  if (i < n4) {
    int c4 = (int)(i & 31) * 4;
    float4 v = ((const float4*)agg)[i];
    float4 xr = ((const float4*)x)[i];
    float4 sc = *(const float4*)(scale + c4);
    float4 sh = *(const float4*)(shift + c4);
    float4 o;
    o.x = fmaxf(v.x * sc.x + sh.x, 0.f) + xr.x;
    o.y = fmaxf(v.y * sc.y + sh.y, 0.f) + xr.y;
    o.z = fmaxf(v.z * sc.z + sh.z, 0.f) + xr.z;
    o.w = fmaxf(v.w * sc.w + sh.w, 0.f) + xr.w;
    ((float4*)out)[i] = o;
  }
}

extern "C" void kernel_launch(void* const* d_in, const int* in_sizes, int n_in,
                              void* d_out, int out_size, void* d_ws, size_t ws_size,
                              hipStream_t stream) {
  const float* x     = (const float*)d_in[0];
  const int*   ei    = (const int*)d_in[1];
  const float* W     = (const float*)d_in[2];
  // d_in[3] = b : cancels exactly in BatchNorm — skipped
  const float* gamma = (const float*)d_in[4];
  const float* beta  = (const float*)d_in[5];
  float* out = (float*)d_out;

  const int N = in_sizes[0] / D;
  const int E = in_sizes[1] / 2;
  const int* row = ei;
  const int* col = ei + E;

  // workspace layout
  unsigned short* g  = (unsigned short*)d_ws;    // N*D bf16 (12.8 MB)
  unsigned short* Wt = g + (size_t)N * D;        // 128*128 bf16 (32 KB)
  float* dinv  = (float*)(Wt + D * D);           // N
  float* sums  = dinv + N;                       // D
  float* sumsq = sums + D;                       // D
  float* scale = sumsq + D;                      // D
  float* shift = scale + D;                      // D
  int*   deg   = (int*)(shift + D);              // N
  int*   ptr   = deg + N;                        // N
  int*   bsum  = ptr + N;                        // 32
  int*   srcs  = bsum + 32;                      // E (3.2 MB)

  hipMemsetAsync(deg, 0, sizeof(int) * (size_t)N, stream);
  hipMemsetAsync(sums, 0, sizeof(float) * 2 * D, stream);

  k_deg<<<(E + 255) / 256, 256, 0, stream>>>(col, deg, E);

  const int nb1 = (N + 2047) / 2048;
  k_scan1<<<nb1, 256, 0, stream>>>(deg, ptr, bsum, dinv, N);
  k_scan2<<<1, 64, 0, stream>>>(bsum, nb1);
  k_scan3<<<(N + 255) / 256, 256, 0, stream>>>(ptr, bsum, N);

  k_prep<<<(D * D) / 256, 256, 0, stream>>>(W, Wt);
  k_mm<<<(N + 63) / 64, 256, 0, stream>>>(x, Wt, dinv, g, N);

  k_bin<<<(E + 255) / 256, 256, 0, stream>>>(row, col, ptr, srcs, E);
  k_agg<<<(N * 64 + 255) / 256, 256, 0, stream>>>(srcs, ptr, (const ushort2*)g, dinv, out, N);

  k_bnstats<<<512, 256, 0, stream>>>(out, sums, sumsq, (long)N * D);
  k_bnfin<<<1, D, 0, stream>>>(sums, sumsq, gamma, beta, scale, shift, 1.0f / (float)N);

  const long n4 = (long)N * (D / 4);
  k_final<<<(int)((n4 + 255) / 256), 256, 0, stream>>>(out, x, scale, shift, out, n4);
}

// Round 13
// 236.713 us; speedup vs baseline: 6.5684x; 1.1060x over previous
//
#include <hip/hip_runtime.h>

#define D 128
#define BN_EPS 1e-5f

typedef __attribute__((ext_vector_type(8))) short short8;
typedef __attribute__((ext_vector_type(4))) float f32x4;

static __device__ __forceinline__ unsigned short f2bf(float f) {
  unsigned u = __float_as_uint(f);
  u += 0x7fff + ((u >> 16) & 1);           // round-to-nearest-even
  return (unsigned short)(u >> 16);
}
static __device__ __forceinline__ float bf2f(unsigned short u) {
  return __uint_as_float(((unsigned)u) << 16);
}

// ---- histogram + slot assignment in one atomic pass ----
// pk[e] = col | slot<<16  (requires N < 65536, max in-degree < 65536)
__global__ __launch_bounds__(256) void k_degslot(const int* __restrict__ col,
                                                 int* __restrict__ deg,
                                                 unsigned* __restrict__ pk, int E) {
  int e = blockIdx.x * 256 + threadIdx.x;
  if (e < E) {
    int c = col[e];
    int s = atomicAdd(&deg[c], 1);
    pk[e] = (unsigned)c | ((unsigned)s << 16);   // coalesced store
  }
}

// ---- exclusive scan of deg -> ptr (2048/block) + fused dinv = rsqrt(deg+1) ----
__global__ __launch_bounds__(256) void k_scan1(const int* __restrict__ deg,
                                               int* __restrict__ ptr,
                                               int* __restrict__ bsum,
                                               float* __restrict__ dinv, int n) {
  __shared__ int lds[256];
  const int tid = threadIdx.x;
  const int base = blockIdx.x * 2048 + tid * 8;
  int v[8];
  int tsum = 0;
#pragma unroll
  for (int j = 0; j < 8; ++j) {
    v[j] = (base + j < n) ? deg[base + j] : 0;
    if (base + j < n) dinv[base + j] = rsqrtf((float)v[j] + 1.0f);
    tsum += v[j];
  }
  lds[tid] = tsum;
  __syncthreads();
#pragma unroll
  for (int off = 1; off < 256; off <<= 1) {
    int t = (tid >= off) ? lds[tid - off] : 0;
    __syncthreads();
    lds[tid] += t;
    __syncthreads();
  }
  int run = lds[tid] - tsum;
  if (tid == 255) bsum[blockIdx.x] = lds[255];
#pragma unroll
  for (int j = 0; j < 8; ++j) {
    if (base + j < n) ptr[base + j] = run;
    run += v[j];
  }
}

__global__ void k_scan2(int* __restrict__ bsum, int nb) {
  if (threadIdx.x == 0) {
    int run = 0;
    for (int i = 0; i < nb; ++i) { int t = bsum[i]; bsum[i] = run; run += t; }
  }
}

__global__ __launch_bounds__(256) void k_scan3(int* __restrict__ ptr,
                                               const int* __restrict__ bsum, int n) {
  int i = blockIdx.x * 256 + threadIdx.x;
  if (i < n) ptr[i] += bsum[i >> 11];
}

// ---- Wt[c][k] = bf16(W[k][c]) ----
__global__ __launch_bounds__(256) void k_prep(const float* __restrict__ W,
                                              unsigned short* __restrict__ Wt) {
  int i = blockIdx.x * 256 + threadIdx.x;   // i = k*128 + c
  int k = i >> 7, c = i & 127;
  Wt[c * D + k] = f2bf(W[i]);
}

// ---- g_bf16 = bf16( (x @ W) * dinv[row] )  via MFMA 16x16x32 bf16 ----
__global__ __launch_bounds__(256) void k_mm(const float* __restrict__ x,
                                            const unsigned short* __restrict__ Wt,
                                            const float* __restrict__ dinv,
                                            unsigned short* __restrict__ g, int n) {
  __shared__ unsigned short wt[D * D];      // 32 KB
  const int tid = threadIdx.x;
  for (int i = tid; i < D * D / 8; i += 256) {      // 2048 x 16B chunks
    int row = i >> 4, c16 = i & 15;
    int dby = (c16 * 16) ^ ((row & 7) << 4);
    *(uint4*)(&wt[row * D + (dby >> 1)]) = ((const uint4*)Wt)[i];
  }
  __syncthreads();

  const int lane = tid & 63;
  const int wave = tid >> 6;
  const int row0 = blockIdx.x * 64 + wave * 16;
  const int lr = lane & 15;
  const int lk = lane >> 4;
  const int arow = row0 + lr;

  short8 a[4] = {};
  if (arow < n) {
    const float* xp = x + (long)arow * D + lk * 8;
#pragma unroll
    for (int kk = 0; kk < 4; ++kk) {
      float4 v0 = *(const float4*)(xp + kk * 32);
      float4 v1 = *(const float4*)(xp + kk * 32 + 4);
      short8 t;
      t[0] = (short)f2bf(v0.x); t[1] = (short)f2bf(v0.y);
      t[2] = (short)f2bf(v0.z); t[3] = (short)f2bf(v0.w);
      t[4] = (short)f2bf(v1.x); t[5] = (short)f2bf(v1.y);
      t[6] = (short)f2bf(v1.z); t[7] = (short)f2bf(v1.w);
      a[kk] = t;
    }
  }

  f32x4 acc[8] = {};
#pragma unroll
  for (int ct = 0; ct < 8; ++ct) {
    const int colt = ct * 16 + lr;
    const unsigned short* wrow = &wt[colt * D];
    const int swz = (colt & 7) << 4;
#pragma unroll
    for (int kk = 0; kk < 4; ++kk) {
      int by = (kk * 64 + lk * 16) ^ swz;
      short8 b = *(const short8*)(&wrow[by >> 1]);
      acc[ct] = __builtin_amdgcn_mfma_f32_16x16x32_bf16(a[kk], b, acc[ct], 0, 0, 0);
    }
  }

  float dv[4];
#pragma unroll
  for (int rr = 0; rr < 4; ++rr) {
    int grow = row0 + lk * 4 + rr;
    dv[rr] = (grow < n) ? dinv[grow] : 0.f;
  }
#pragma unroll
  for (int ct = 0; ct < 8; ++ct) {
#pragma unroll
    for (int rr = 0; rr < 4; ++rr) {
      int grow = row0 + lk * 4 + rr;
      if (grow < n)
        g[(long)grow * D + ct * 16 + lr] = f2bf(acc[ct][rr] * dv[rr]);
    }
  }
}

// ---- atomic-free binning: srcs[ptr[c] + slot] = row ----
__global__ __launch_bounds__(256) void k_bin2(const int* __restrict__ row,
                                              const unsigned* __restrict__ pk,
                                              const int* __restrict__ ptr,
                                              int* __restrict__ srcs, int E) {
  int e = blockIdx.x * 256 + threadIdx.x;
  if (e < E) {
    unsigned p = pk[e];
    int c = (int)(p & 0xFFFFu);
    int s = (int)(p >> 16);
    srcs[ptr[c] + s] = row[e];
  }
}

// ---- per-node gather-reduce over bf16 g: out[c] = dinv[c]*(sum g[srcs] + g[c]) ----
// node c's list spans [ptr[c], ptr[c+1]) with sentinel E (ptr is unmutated)
__global__ __launch_bounds__(256) void k_agg(const int* __restrict__ srcs,
                                             const int* __restrict__ ptr,
                                             const ushort2* __restrict__ g2,
                                             const float* __restrict__ dinv,
                                             float* __restrict__ out, int n, int Etot) {
  int wid = (blockIdx.x * 256 + threadIdx.x) >> 6;
  if (wid >= n) return;
  int lane = threadIdx.x & 63;
  int start = ptr[wid];
  int end = (wid == n - 1) ? Etot : ptr[wid + 1];
  const ushort2* gl = g2 + lane;             // row stride = 64 ushort2
  ushort2 sv = gl[(long)wid * 64];
  float ax = bf2f(sv.x), ay = bf2f(sv.y);    // self-loop term
  int i = start;
  for (; i + 3 < end; i += 4) {
    ushort2 v0 = gl[(long)srcs[i] * 64];
    ushort2 v1 = gl[(long)srcs[i + 1] * 64];
    ushort2 v2 = gl[(long)srcs[i + 2] * 64];
    ushort2 v3 = gl[(long)srcs[i + 3] * 64];
    ax += bf2f(v0.x) + bf2f(v1.x) + bf2f(v2.x) + bf2f(v3.x);
    ay += bf2f(v0.y) + bf2f(v1.y) + bf2f(v2.y) + bf2f(v3.y);
  }
  for (; i < end; ++i) {
    ushort2 v0 = gl[(long)srcs[i] * 64];
    ax += bf2f(v0.x);
    ay += bf2f(v0.y);
  }
  float dc = dinv[wid];
  *(float2*)(out + (long)wid * D + lane * 2) = make_float2(ax * dc, ay * dc);
}

// ---- per-column sums for BN ----
__global__ __launch_bounds__(256) void k_bnstats(const float* __restrict__ agg,
                                                 float* __restrict__ sums,
                                                 float* __restrict__ sumsq, long total) {
  float s = 0.f, sq = 0.f;
  for (long i = (long)blockIdx.x * 256 + threadIdx.x; i < total; i += (long)gridDim.x * 256) {
    float v = agg[i];
    s += v; sq += v * v;
  }
  __shared__ float rs[256], rq[256];
  int tid = threadIdx.x;
  rs[tid] = s; rq[tid] = sq;
  __syncthreads();
  if (tid < 128) {
    atomicAdd(&sums[tid], rs[tid] + rs[tid + 128]);
    atomicAdd(&sumsq[tid], rq[tid] + rq[tid + 128]);
  }
}

// ---- fold stats (bias b cancels in BN exactly) ----
__global__ void k_bnfin(const float* __restrict__ sums, const float* __restrict__ sumsq,
                        const float* __restrict__ gamma, const float* __restrict__ beta,
                        float* __restrict__ scale, float* __restrict__ shift, float invN) {
  int d = threadIdx.x;
  float mean = sums[d] * invN;
  float var = sumsq[d] * invN - mean * mean;
  float sc = gamma[d] * rsqrtf(var + BN_EPS);
  scale[d] = sc;
  shift[d] = beta[d] - mean * sc;
}

// ---- out = relu(agg*scale + shift) + x ----
__global__ __launch_bounds__(256) void k_final(const float* __restrict__ agg,
                                               const float* __restrict__ x,
                                               const float* __restrict__ scale,
                                               const float* __restrict__ shift,
                                               float* __restrict__ out, long n4) {
  long i = (long)blockIdx.x * 256 + threadIdx.x;
  if (i < n4) {
    int c4 = (int)(i & 31) * 4;
    float4 v = ((const float4*)agg)[i];
    float4 xr = ((const float4*)x)[i];
    float4 sc = *(const float4*)(scale + c4);
    float4 sh = *(const float4*)(shift + c4);
    float4 o;
    o.x = fmaxf(v.x * sc.x + sh.x, 0.f) + xr.x;
    o.y = fmaxf(v.y * sc.y + sh.y, 0.f) + xr.y;
    o.z = fmaxf(v.z * sc.z + sh.z, 0.f) + xr.z;
    o.w = fmaxf(v.w * sc.w + sh.w, 0.f) + xr.w;
    ((float4*)out)[i] = o;
  }
}

extern "C" void kernel_launch(void* const* d_in, const int* in_sizes, int n_in,
                              void* d_out, int out_size, void* d_ws, size_t ws_size,
                              hipStream_t stream) {
  const float* x     = (const float*)d_in[0];
  const int*   ei    = (const int*)d_in[1];
  const float* W     = (const float*)d_in[2];
  // d_in[3] = b : cancels exactly in BatchNorm — skipped
  const float* gamma = (const float*)d_in[4];
  const float* beta  = (const float*)d_in[5];
  float* out = (float*)d_out;

  const int N = in_sizes[0] / D;
  const int E = in_sizes[1] / 2;
  const int* row = ei;
  const int* col = ei + E;

  // workspace layout
  unsigned short* g  = (unsigned short*)d_ws;    // N*D bf16 (12.8 MB)
  unsigned short* Wt = g + (size_t)N * D;        // 128*128 bf16 (32 KB)
  float* dinv  = (float*)(Wt + D * D);           // N
  float* sums  = dinv + N;                       // D
  float* sumsq = sums + D;                       // D
  float* scale = sumsq + D;                      // D
  float* shift = scale + D;                      // D
  int*   deg   = (int*)(shift + D);              // N
  int*   ptr   = deg + N;                        // N
  int*   bsum  = ptr + N;                        // 32
  int*   srcs  = bsum + 32;                      // E (3.2 MB)
  unsigned* pk = (unsigned*)(srcs + E);          // E (3.2 MB)

  hipMemsetAsync(deg, 0, sizeof(int) * (size_t)N, stream);
  hipMemsetAsync(sums, 0, sizeof(float) * 2 * D, stream);

  k_degslot<<<(E + 255) / 256, 256, 0, stream>>>(col, deg, pk, E);

  const int nb1 = (N + 2047) / 2048;
  k_scan1<<<nb1, 256, 0, stream>>>(deg, ptr, bsum, dinv, N);
  k_scan2<<<1, 64, 0, stream>>>(bsum, nb1);
  k_scan3<<<(N + 255) / 256, 256, 0, stream>>>(ptr, bsum, N);

  k_prep<<<(D * D) / 256, 256, 0, stream>>>(W, Wt);
  k_mm<<<(N + 63) / 64, 256, 0, stream>>>(x, Wt, dinv, g, N);

  k_bin2<<<(E + 255) / 256, 256, 0, stream>>>(row, pk, ptr, srcs, E);
  k_agg<<<(N * 64 + 255) / 256, 256, 0, stream>>>(srcs, ptr, (const ushort2*)g, dinv, out, N, E);

  k_bnstats<<<512, 256, 0, stream>>>(out, sums, sumsq, (long)N * D);
  k_bnfin<<<1, D, 0, stream>>>(sums, sumsq, gamma, beta, scale, shift, 1.0f / (float)N);

  const long n4 = (long)N * (D / 4);
  k_final<<<(int)((n4 + 255) / 256), 256, 0, stream>>>(out, x, scale, shift, out, n4);
}

// Round 15
// 235.490 us; speedup vs baseline: 6.6025x; 1.0052x over previous
//
#include <hip/hip_runtime.h>

#define D 128
#define BN_EPS 1e-5f

typedef __attribute__((ext_vector_type(8))) short short8;
typedef __attribute__((ext_vector_type(4))) float f32x4;

static __device__ __forceinline__ unsigned short f2bf(float f) {
  unsigned u = __float_as_uint(f);
  u += 0x7fff + ((u >> 16) & 1);           // round-to-nearest-even
  return (unsigned short)(u >> 16);
}
static __device__ __forceinline__ float bf2f(unsigned short u) {
  return __uint_as_float(((unsigned)u) << 16);
}

// ---- histogram + slot assignment, 4 edges/thread for MLP ----
// pk[e] = col | slot<<16  (N < 65536, max in-degree < 65536)
__global__ __launch_bounds__(256) void k_degslot(const int* __restrict__ col,
                                                 int* __restrict__ deg,
                                                 unsigned* __restrict__ pk, int E) {
  int e0 = (blockIdx.x * 256 + threadIdx.x) * 4;
  if (e0 + 3 < E) {
    int4 c = *(const int4*)(col + e0);
    int s0 = atomicAdd(&deg[c.x], 1);
    int s1 = atomicAdd(&deg[c.y], 1);
    int s2 = atomicAdd(&deg[c.z], 1);
    int s3 = atomicAdd(&deg[c.w], 1);
    uint4 p;
    p.x = (unsigned)c.x | ((unsigned)s0 << 16);
    p.y = (unsigned)c.y | ((unsigned)s1 << 16);
    p.z = (unsigned)c.z | ((unsigned)s2 << 16);
    p.w = (unsigned)c.w | ((unsigned)s3 << 16);
    *(uint4*)(pk + e0) = p;
  } else {
    for (int e = e0; e < E; ++e) {
      int c = col[e];
      int s = atomicAdd(&deg[c], 1);
      pk[e] = (unsigned)c | ((unsigned)s << 16);
    }
  }
}

// ---- exclusive scan of deg -> ptr (2048/block) + fused dinv = rsqrt(deg+1) ----
__global__ __launch_bounds__(256) void k_scan1(const int* __restrict__ deg,
                                               int* __restrict__ ptr,
                                               int* __restrict__ bsum,
                                               float* __restrict__ dinv, int n) {
  __shared__ int lds[256];
  const int tid = threadIdx.x;
  const int base = blockIdx.x * 2048 + tid * 8;
  int v[8];
  int tsum = 0;
#pragma unroll
  for (int j = 0; j < 8; ++j) {
    v[j] = (base + j < n) ? deg[base + j] : 0;
    if (base + j < n) dinv[base + j] = rsqrtf((float)v[j] + 1.0f);
    tsum += v[j];
  }
  lds[tid] = tsum;
  __syncthreads();
#pragma unroll
  for (int off = 1; off < 256; off <<= 1) {
    int t = (tid >= off) ? lds[tid - off] : 0;
    __syncthreads();
    lds[tid] += t;
    __syncthreads();
  }
  int run = lds[tid] - tsum;
  if (tid == 255) bsum[blockIdx.x] = lds[255];
#pragma unroll
  for (int j = 0; j < 8; ++j) {
    if (base + j < n) ptr[base + j] = run;
    run += v[j];
  }
}

__global__ void k_scan2(int* __restrict__ bsum, int nb) {
  if (threadIdx.x == 0) {
    int run = 0;
    for (int i = 0; i < nb; ++i) { int t = bsum[i]; bsum[i] = run; run += t; }
  }
}

__global__ __launch_bounds__(256) void k_scan3(int* __restrict__ ptr,
                                               const int* __restrict__ bsum, int n) {
  int i = blockIdx.x * 256 + threadIdx.x;
  if (i < n) ptr[i] += bsum[i >> 11];
}

// ---- Wt[c][k] = bf16(W[k][c]) ----
__global__ __launch_bounds__(256) void k_prep(const float* __restrict__ W,
                                              unsigned short* __restrict__ Wt) {
  int i = blockIdx.x * 256 + threadIdx.x;   // i = k*128 + c
  int k = i >> 7, c = i & 127;
  Wt[c * D + k] = f2bf(W[i]);
}

// ---- g_bf16 = bf16( (x @ W) * dinv[row] )  via MFMA 16x16x32 bf16 ----
__global__ __launch_bounds__(256) void k_mm(const float* __restrict__ x,
                                            const unsigned short* __restrict__ Wt,
                                            const float* __restrict__ dinv,
                                            unsigned short* __restrict__ g, int n) {
  __shared__ unsigned short wt[D * D];      // 32 KB
  const int tid = threadIdx.x;
  for (int i = tid; i < D * D / 8; i += 256) {      // 2048 x 16B chunks
    int row = i >> 4, c16 = i & 15;
    int dby = (c16 * 16) ^ ((row & 7) << 4);
    *(uint4*)(&wt[row * D + (dby >> 1)]) = ((const uint4*)Wt)[i];
  }
  __syncthreads();

  const int lane = tid & 63;
  const int wave = tid >> 6;
  const int row0 = blockIdx.x * 64 + wave * 16;
  const int lr = lane & 15;
  const int lk = lane >> 4;
  const int arow = row0 + lr;

  short8 a[4] = {};
  if (arow < n) {
    const float* xp = x + (long)arow * D + lk * 8;
#pragma unroll
    for (int kk = 0; kk < 4; ++kk) {
      float4 v0 = *(const float4*)(xp + kk * 32);
      float4 v1 = *(const float4*)(xp + kk * 32 + 4);
      short8 t;
      t[0] = (short)f2bf(v0.x); t[1] = (short)f2bf(v0.y);
      t[2] = (short)f2bf(v0.z); t[3] = (short)f2bf(v0.w);
      t[4] = (short)f2bf(v1.x); t[5] = (short)f2bf(v1.y);
      t[6] = (short)f2bf(v1.z); t[7] = (short)f2bf(v1.w);
      a[kk] = t;
    }
  }

  f32x4 acc[8] = {};
#pragma unroll
  for (int ct = 0; ct < 8; ++ct) {
    const int colt = ct * 16 + lr;
    const unsigned short* wrow = &wt[colt * D];
    const int swz = (colt & 7) << 4;
#pragma unroll
    for (int kk = 0; kk < 4; ++kk) {
      int by = (kk * 64 + lk * 16) ^ swz;
      short8 b = *(const short8*)(&wrow[by >> 1]);
      acc[ct] = __builtin_amdgcn_mfma_f32_16x16x32_bf16(a[kk], b, acc[ct], 0, 0, 0);
    }
  }

  float dv[4];
#pragma unroll
  for (int rr = 0; rr < 4; ++rr) {
    int grow = row0 + lk * 4 + rr;
    dv[rr] = (grow < n) ? dinv[grow] : 0.f;
  }
#pragma unroll
  for (int ct = 0; ct < 8; ++ct) {
#pragma unroll
    for (int rr = 0; rr < 4; ++rr) {
      int grow = row0 + lk * 4 + rr;
      if (grow < n)
        g[(long)grow * D + ct * 16 + lr] = f2bf(acc[ct][rr] * dv[rr]);
    }
  }
}

// ---- atomic-free binning, 4 edges/thread: srcs[ptr[c] + slot] = row ----
__global__ __launch_bounds__(256) void k_bin2(const int* __restrict__ row,
                                              const unsigned* __restrict__ pk,
                                              const int* __restrict__ ptr,
                                              int* __restrict__ srcs, int E) {
  int e0 = (blockIdx.x * 256 + threadIdx.x) * 4;
  if (e0 + 3 < E) {
    int4 r = *(const int4*)(row + e0);
    uint4 p = *(const uint4*)(pk + e0);
    int b0 = ptr[p.x & 0xFFFFu], b1 = ptr[p.y & 0xFFFFu];
    int b2 = ptr[p.z & 0xFFFFu], b3 = ptr[p.w & 0xFFFFu];
    srcs[b0 + (int)(p.x >> 16)] = r.x;
    srcs[b1 + (int)(p.y >> 16)] = r.y;
    srcs[b2 + (int)(p.z >> 16)] = r.z;
    srcs[b3 + (int)(p.w >> 16)] = r.w;
  } else {
    for (int e = e0; e < E; ++e) {
      unsigned p = pk[e];
      srcs[ptr[p & 0xFFFFu] + (int)(p >> 16)] = row[e];
    }
  }
}

// ---- per-node gather-reduce: 32 lanes x ushort4 per row, 2 edges in flight ----
// node c's list spans [ptr[c], ptr[c+1]) with sentinel E (ptr unmutated)
__global__ __launch_bounds__(256) void k_agg(const int* __restrict__ srcs,
                                             const int* __restrict__ ptr,
                                             const ushort4* __restrict__ g4,
                                             const float* __restrict__ dinv,
                                             float* __restrict__ out, int n, int Etot) {
  int wid = (blockIdx.x * 256 + threadIdx.x) >> 6;
  if (wid >= n) return;
  int lane = threadIdx.x & 63;
  int l32 = lane & 31;
  int half = lane >> 5;                      // 0: even edges, 1: odd edges
  int start = ptr[wid];
  int end = (wid == n - 1) ? Etot : ptr[wid + 1];
  const ushort4* gl = g4 + l32;              // row stride = 32 ushort4

  float a0 = 0.f, a1 = 0.f, a2 = 0.f, a3 = 0.f;
  if (half == 0) {                           // self-loop term in half 0
    ushort4 sv = gl[(long)wid * 32];
    a0 = bf2f(sv.x); a1 = bf2f(sv.y); a2 = bf2f(sv.z); a3 = bf2f(sv.w);
  }
  int i = start + half;
  for (; i + 2 < end; i += 4) {              // 2 gathers in flight per half
    ushort4 v0 = gl[(long)srcs[i] * 32];
    ushort4 v1 = gl[(long)srcs[i + 2] * 32];
    a0 += bf2f(v0.x) + bf2f(v1.x);
    a1 += bf2f(v0.y) + bf2f(v1.y);
    a2 += bf2f(v0.z) + bf2f(v1.z);
    a3 += bf2f(v0.w) + bf2f(v1.w);
  }
  if (i < end) {
    ushort4 v0 = gl[(long)srcs[i] * 32];
    a0 += bf2f(v0.x); a1 += bf2f(v0.y); a2 += bf2f(v0.z); a3 += bf2f(v0.w);
  }
  // combine halves (lane <-> lane^32)
  a0 += __shfl(a0, lane ^ 32);
  a1 += __shfl(a1, lane ^ 32);
  a2 += __shfl(a2, lane ^ 32);
  a3 += __shfl(a3, lane ^ 32);
  if (half == 0) {
    float dc = dinv[wid];
    *(float4*)(out + (long)wid * D + l32 * 4) =
        make_float4(a0 * dc, a1 * dc, a2 * dc, a3 * dc);
  }
}

// ---- per-column sums for BN ----
__global__ __launch_bounds__(256) void k_bnstats(const float* __restrict__ agg,
                                                 float* __restrict__ sums,
                                                 float* __restrict__ sumsq, long total) {
  float s = 0.f, sq = 0.f;
  for (long i = (long)blockIdx.x * 256 + threadIdx.x; i < total; i += (long)gridDim.x * 256) {
    float v = agg[i];
    s += v; sq += v * v;
  }
  __shared__ float rs[256], rq[256];
  int tid = threadIdx.x;
  rs[tid] = s; rq[tid] = sq;
  __syncthreads();
  if (tid < 128) {
    atomicAdd(&sums[tid], rs[tid] + rs[tid + 128]);
    atomicAdd(&sumsq[tid], rq[tid] + rq[tid + 128]);
  }
}

// ---- fold stats (bias b cancels in BN exactly) ----
__global__ void k_bnfin(const float* __restrict__ sums, const float* __restrict__ sumsq,
                        const float* __restrict__ gamma, const float* __restrict__ beta,
                        float* __restrict__ scale, float* __restrict__ shift, float invN) {
  int d = threadIdx.x;
  float mean = sums[d] * invN;
  float var = sumsq[d] * invN - mean * mean;
  float sc = gamma[d] * rsqrtf(var + BN_EPS);
  scale[d] = sc;
  shift[d] = beta[d] - mean * sc;
}

// ---- out = relu(agg*scale + shift) + x ----
__global__ __launch_bounds__(256) void k_final(const float* __restrict__ agg,
                                               const float* __restrict__ x,
                                               const float* __restrict__ scale,
                                               const float* __restrict__ shift,
                                               float* __restrict__ out, long n4) {
  long i = (long)blockIdx.x * 256 + threadIdx.x;
  if (i < n4) {
    int c4 = (int)(i & 31) * 4;
    float4 v = ((const float4*)agg)[i];
    float4 xr = ((const float4*)x)[i];
    float4 sc = *(const float4*)(scale + c4);
    float4 sh = *(const float4*)(shift + c4);
    float4 o;
    o.x = fmaxf(v.x * sc.x + sh.x, 0.f) + xr.x;
    o.y = fmaxf(v.y * sc.y + sh.y, 0.f) + xr.y;
    o.z = fmaxf(v.z * sc.z + sh.z, 0.f) + xr.z;
    o.w = fmaxf(v.w * sc.w + sh.w, 0.f) + xr.w;
    ((float4*)out)[i] = o;
  }
}

extern "C" void kernel_launch(void* const* d_in, const int* in_sizes, int n_in,
                              void* d_out, int out_size, void* d_ws, size_t ws_size,
                              hipStream_t stream) {
  const float* x     = (const float*)d_in[0];
  const int*   ei    = (const int*)d_in[1];
  const float* W     = (const float*)d_in[2];
  // d_in[3] = b : cancels exactly in BatchNorm — skipped
  const float* gamma = (const float*)d_in[4];
  const float* beta  = (const float*)d_in[5];
  float* out = (float*)d_out;

  const int N = in_sizes[0] / D;
  const int E = in_sizes[1] / 2;
  const int* row = ei;
  const int* col = ei + E;

  // workspace layout
  unsigned short* g  = (unsigned short*)d_ws;    // N*D bf16 (12.8 MB)
  unsigned short* Wt = g + (size_t)N * D;        // 128*128 bf16 (32 KB)
  float* dinv  = (float*)(Wt + D * D);           // N
  float* sums  = dinv + N;                       // D
  float* sumsq = sums + D;                       // D
  float* scale = sumsq + D;                      // D
  float* shift = scale + D;                      // D
  int*   deg   = (int*)(shift + D);              // N
  int*   ptr   = deg + N;                        // N
  int*   bsum  = ptr + N;                        // 32
  int*   srcs  = bsum + 32;                      // E (3.2 MB)
  unsigned* pk = (unsigned*)(srcs + E);          // E (3.2 MB)

  hipMemsetAsync(deg, 0, sizeof(int) * (size_t)N, stream);
  hipMemsetAsync(sums, 0, sizeof(float) * 2 * D, stream);

  k_degslot<<<(E / 4 + 255) / 256, 256, 0, stream>>>(col, deg, pk, E);

  const int nb1 = (N + 2047) / 2048;
  k_scan1<<<nb1, 256, 0, stream>>>(deg, ptr, bsum, dinv, N);
  k_scan2<<<1, 64, 0, stream>>>(bsum, nb1);
  k_scan3<<<(N + 255) / 256, 256, 0, stream>>>(ptr, bsum, N);

  k_prep<<<(D * D) / 256, 256, 0, stream>>>(W, Wt);
  k_mm<<<(N + 63) / 64, 256, 0, stream>>>(x, Wt, dinv, g, N);

  k_bin2<<<(E / 4 + 255) / 256, 256, 0, stream>>>(row, pk, ptr, srcs, E);
  k_agg<<<(N * 64 + 255) / 256, 256, 0, stream>>>(srcs, ptr, (const ushort4*)g, dinv, out, N, E);

  k_bnstats<<<512, 256, 0, stream>>>(out, sums, sumsq, (long)N * D);
  k_bnfin<<<1, D, 0, stream>>>(sums, sumsq, gamma, beta, scale, shift, 1.0f / (float)N);

  const long n4 = (long)N * (D / 4);
  k_final<<<(int)((n4 + 255) / 256), 256, 0, stream>>>(out, x, scale, shift, out, n4);
}